// Round 4
// baseline (940.965 us; speedup 1.0000x reference)
//
#include <hip/hip_runtime.h>

#define BB 16
#define NN 2048
#define MM 2048
#define EPSF 1e-9f

constexpr int WAVES = 4;   // waves per block
constexpr int RB = 8;      // rows per wave (row passes)
constexpr int CB = 8;      // cols per wave (col pass)

// Workspace layout:
//  P1[b*NN+i] = float4(x1, y1, z1, scale_i)   -- scale written by row_pass
//  P2[b*MM+l] = float4(x2, y2, z2, remR_l)    -- remR  written by col_pass
//  remL[b*NN+i]
//  Pcol[b*MM+l] = remR_l * cons_l             -- written by col_pass

// ---------------- init: AoS->packed float4 + state init ----------------
__global__ __launch_bounds__(256) void init_kernel(
    const float* __restrict__ xyz1, const float* __restrict__ xyz2,
    float4* __restrict__ P1, float4* __restrict__ P2,
    float* __restrict__ remL, float* __restrict__ out)
{
    const int t = blockIdx.x * 256 + threadIdx.x;
    if (t < BB * NN) {
        P1[t] = make_float4(xyz1[3*t+0], xyz1[3*t+1], xyz1[3*t+2], 0.0f);
        remL[t] = 1.0f;   // max(n,m)/n
    }
    if (t < BB * MM) {
        P2[t] = make_float4(xyz2[3*t+0], xyz2[3*t+1], xyz2[3*t+2], 1.0f); // .w = remR
    }
    if (t < BB) out[t] = 0.0f;
}

// ---------------- row pass ----------------
// MODE 0: first pass. rowsum at coefNext only (remL == 1 from init).
// MODE 1: fused remainL-update (level j, via e_next^4) + new scale (level j+1).
// MODE 2: last fused pass: e_prev = exp2(coefPrev*d2) direct, e_next = 1 (level 0).
template<int MODE>
__global__ __launch_bounds__(256) void row_pass(
    const float4* __restrict__ P2, const float* __restrict__ Pcol,
    float4* __restrict__ P1, float* __restrict__ remL,
    float coefPrev, float coefNext)
{
    __shared__ float4 sP2[MM];     // 32 KB: x2,y2,z2,remR
    __shared__ float  sPc[MM];     // 8 KB:  remR*cons

    const int lane = threadIdx.x & 63;
    const int wave = threadIdx.x >> 6;
    const int bpb = NN / (WAVES * RB);          // blocks per batch = 64
    const int batch = blockIdx.x / bpb;
    const int rblk  = blockIdx.x % bpb;
    const int r0 = rblk * (WAVES * RB) + wave * RB;

    // ---- stage the streamed arrays into LDS (coalesced) ----
    {
        const float4* p2b = P2 + batch * MM;
        const float*  pcb = Pcol + batch * MM;
        for (int t = threadIdx.x; t < MM; t += 256) {
            sP2[t] = p2b[t];
            if (MODE != 0) sPc[t] = pcb[t];
        }
    }

    const float4* p1b = P1 + batch * NN;
    float px[RB], py[RB], pz[RB], psc[RB];
#pragma unroll
    for (int r = 0; r < RB; ++r) {
        const float4 q = p1b[r0 + r];
        px[r] = q.x; py[r] = q.y; pz[r] = q.z;
        psc[r] = (MODE != 0) ? q.w : 0.0f;      // previous scale
    }

    __syncthreads();

    const float cf = (MODE == 2) ? coefPrev : coefNext;

    float u[RB], rs[RB];
#pragma unroll
    for (int r = 0; r < RB; ++r) { u[r] = 0.0f; rs[r] = 0.0f; }

    for (int cb = 0; cb < MM; cb += 128) {
        const float4 qa = sP2[cb + lane];
        const float4 qb = sP2[cb + 64 + lane];
        const float Pca = (MODE != 0) ? sPc[cb + lane] : 0.0f;
        const float Pcb = (MODE != 0) ? sPc[cb + 64 + lane] : 0.0f;
        if (MODE == 2) rs[0] += qa.w + qb.w;    // e_next = 1

        // phase 1: all squared distances (full-rate only)
        float d2a[RB], d2b[RB];
#pragma unroll
        for (int r = 0; r < RB; ++r) {
            float dx = px[r] - qa.x, dy = py[r] - qa.y, dz = pz[r] - qa.z;
            d2a[r] = dx*dx + dy*dy + dz*dz;
            dx = px[r] - qb.x; dy = py[r] - qb.y; dz = pz[r] - qb.z;
            d2b[r] = dx*dx + dy*dy + dz*dz;
        }
        // phase 2: all transcendentals back-to-back
        float ea[RB], eb[RB];
#pragma unroll
        for (int r = 0; r < RB; ++r) {
            ea[r] = __builtin_amdgcn_exp2f(cf * d2a[r]);
            eb[r] = __builtin_amdgcn_exp2f(cf * d2b[r]);
        }
        // phase 3: accumulate (full-rate only)
#pragma unroll
        for (int r = 0; r < RB; ++r) {
            if (MODE == 0) {
                rs[r] = fmaf(ea[r], qa.w, rs[r]);
                rs[r] = fmaf(eb[r], qb.w, rs[r]);
            } else if (MODE == 1) {
                const float e2a = ea[r] * ea[r], e4a = e2a * e2a;
                const float e2b = eb[r] * eb[r], e4b = e2b * e2b;
                u[r]  = fmaf(e4a, Pca, u[r]);
                u[r]  = fmaf(e4b, Pcb, u[r]);
                rs[r] = fmaf(ea[r], qa.w, rs[r]);
                rs[r] = fmaf(eb[r], qb.w, rs[r]);
            } else {
                u[r]  = fmaf(ea[r], Pca, u[r]);
                u[r]  = fmaf(eb[r], Pcb, u[r]);
            }
        }
    }

#pragma unroll
    for (int r = 0; r < RB; ++r) {
#pragma unroll
        for (int off = 32; off > 0; off >>= 1) {
            if (MODE != 2 || r == 0) rs[r] += __shfl_xor(rs[r], off, 64);
            if (MODE != 0) u[r] += __shfl_xor(u[r], off, 64);
        }
    }

    float* p1w = (float*)P1;                    // scalar access to .w lanes
#pragma unroll
    for (int r = 0; r < RB; ++r) {
        if (lane == r) {
            const int row = batch * NN + r0 + r;
            const float rsum = (MODE == 2) ? rs[0] : rs[r];
            float L;
            if (MODE == 0) {
                L = remL[row];
            } else {
                L = fmaxf(remL[row] - psc[r] * u[r], 0.0f);
                remL[row] = L;
            }
            p1w[4 * row + 3] = L / (rsum + EPSF);   // scale
        }
    }
}

// ---------------- col pass ----------------
__global__ __launch_bounds__(256) void col_pass(
    const float4* __restrict__ P1,
    float4* __restrict__ P2, float* __restrict__ Pcol,
    float* __restrict__ out, float coef)
{
    __shared__ float4 sP1[NN];     // 32 KB: x1,y1,z1,scale

    const int lane = threadIdx.x & 63;
    const int wave = threadIdx.x >> 6;
    const int bpb = MM / (WAVES * CB);          // 64
    const int batch = blockIdx.x / bpb;
    const int cblk  = blockIdx.x % bpb;
    const int c0 = cblk * (WAVES * CB) + wave * CB;

    // ---- stage P1 into LDS (coalesced) ----
    {
        const float4* p1b = P1 + batch * NN;
        for (int t = threadIdx.x; t < NN; t += 256) sP1[t] = p1b[t];
    }

    const float4* p2b = P2 + batch * MM;
    float qx[CB], qy[CB], qz[CB];
#pragma unroll
    for (int cc = 0; cc < CB; ++cc) {
        const float4 q = p2b[c0 + cc];
        qx[cc] = q.x; qy[cc] = q.y; qz[cc] = q.z;
    }

    __syncthreads();

    float s[CB], t[CB];
#pragma unroll
    for (int cc = 0; cc < CB; ++cc) { s[cc] = 0.0f; t[cc] = 0.0f; }

    for (int ib = 0; ib < NN; ib += 128) {
        const float4 a0 = sP1[ib + lane];
        const float4 a1 = sP1[ib + 64 + lane];

        // phase 1: all squared distances (full-rate only)
        float d2a[CB], d2b[CB];
#pragma unroll
        for (int cc = 0; cc < CB; ++cc) {
            float dx = a0.x - qx[cc], dy = a0.y - qy[cc], dz = a0.z - qz[cc];
            d2a[cc] = dx*dx + dy*dy + dz*dz;
            dx = a1.x - qx[cc]; dy = a1.y - qy[cc]; dz = a1.z - qz[cc];
            d2b[cc] = dx*dx + dy*dy + dz*dz;
        }
        // phase 2: all transcendentals back-to-back
        float ea[CB], eb[CB], ra[CB], rb[CB];
#pragma unroll
        for (int cc = 0; cc < CB; ++cc) {
            ea[cc] = __builtin_amdgcn_exp2f(coef * d2a[cc]);
            eb[cc] = __builtin_amdgcn_exp2f(coef * d2b[cc]);
        }
#pragma unroll
        for (int cc = 0; cc < CB; ++cc) {
            ra[cc] = __builtin_amdgcn_sqrtf(d2a[cc]);
            rb[cc] = __builtin_amdgcn_sqrtf(d2b[cc]);
        }
        // phase 3: accumulate (full-rate only)
#pragma unroll
        for (int cc = 0; cc < CB; ++cc) {
            const float sea = a0.w * ea[cc];
            const float seb = a1.w * eb[cc];
            s[cc] += sea;
            s[cc] += seb;
            t[cc] = fmaf(sea, ra[cc], t[cc]);
            t[cc] = fmaf(seb, rb[cc], t[cc]);
        }
    }

#pragma unroll
    for (int cc = 0; cc < CB; ++cc) {
#pragma unroll
        for (int off = 32; off > 0; off >>= 1) {
            s[cc] += __shfl_xor(s[cc], off, 64);
            t[cc] += __shfl_xor(t[cc], off, 64);
        }
    }

    float* p2w = (float*)P2;
    float costw = 0.0f;
#pragma unroll
    for (int cc = 0; cc < CB; ++cc) {
        if (lane == cc) {
            const int col = batch * MM + c0 + cc;
            const float R = p2w[4 * col + 3];   // remR
            const float sumr = s[cc] * R;
            const float cons = fminf(R / (sumr + EPSF), 1.0f);
            costw = R * cons * t[cc];
            Pcol[col] = R * cons;
            p2w[4 * col + 3] = fmaxf(R - sumr * cons, 0.0f);
        }
    }
#pragma unroll
    for (int off = 32; off > 0; off >>= 1) costw += __shfl_xor(costw, off, 64);
    if (lane == 0) atomicAdd(out + batch, costw);
}

extern "C" void kernel_launch(void* const* d_in, const int* in_sizes, int n_in,
                              void* d_out, int out_size, void* d_ws, size_t ws_size,
                              hipStream_t stream)
{
    const float* xyz1 = (const float*)d_in[0];
    const float* xyz2 = (const float*)d_in[1];
    float* out = (float*)d_out;

    const int BN = BB * NN, BM = BB * MM;
    float4* P1 = (float4*)d_ws;
    float4* P2 = P1 + BN;
    float*  remL = (float*)(P2 + BM);
    float*  Pcol = remL + BN;

    init_kernel<<<dim3((BN + 255) / 256), dim3(256), 0, stream>>>(
        xyz1, xyz2, P1, P2, remL, out);

    // levels: j = 7..-1 -> -(4^j), then 0.  coef = level * log2(e)
    float coef[10];
    const double lv[10] = {-16384.0, -4096.0, -1024.0, -256.0, -64.0,
                           -16.0, -4.0, -1.0, -0.25, 0.0};
    for (int i = 0; i < 10; ++i) coef[i] = (float)(lv[i] * 1.4426950408889634);

    dim3 grid(BB * (NN / (WAVES * RB)));   // 1024
    dim3 blk(256);

    row_pass<0><<<grid, blk, 0, stream>>>(P2, Pcol, P1, remL, 0.0f, coef[0]);
    for (int j = 0; j < 10; ++j) {
        col_pass<<<grid, blk, 0, stream>>>(P1, P2, Pcol, out, coef[j]);
        if (j < 8) {
            row_pass<1><<<grid, blk, 0, stream>>>(P2, Pcol, P1, remL, coef[j], coef[j+1]);
        } else if (j == 8) {
            row_pass<2><<<grid, blk, 0, stream>>>(P2, Pcol, P1, remL, coef[8], 0.0f);
        }
    }
}

// Round 5
// 642.495 us; speedup vs baseline: 1.4645x; 1.4645x over previous
//
#include <hip/hip_runtime.h>

#define BB 16
#define NN 2048
#define MM 2048
#define EPSF 1e-9f

constexpr int WAVES = 4;   // waves per block (row pass)
constexpr int RB = 8;      // rows per wave (row passes)
constexpr int CH = 128;    // i-chunk length (col pass A)

// Workspace layout:
//  P1[b*NN+i] = float4(x1, y1, z1, scale_i)   -- scale written by row_pass
//  P2[b*MM+l] = float4(x2, y2, z2, remR_l)    -- remR updated by colB
//  remL[b*NN+i]
//  Pcol[b*MM+l] = remR_l * cons_l             -- written by colB
//  stS/stT[b*MM+l]                            -- partial sums, zeroed by init/colB

// ---------------- init ----------------
__global__ __launch_bounds__(256) void init_kernel(
    const float* __restrict__ xyz1, const float* __restrict__ xyz2,
    float4* __restrict__ P1, float4* __restrict__ P2,
    float* __restrict__ remL, float* __restrict__ stS, float* __restrict__ stT,
    float* __restrict__ out)
{
    const int t = blockIdx.x * 256 + threadIdx.x;
    if (t < BB * NN) {
        P1[t] = make_float4(xyz1[3*t+0], xyz1[3*t+1], xyz1[3*t+2], 0.0f);
        remL[t] = 1.0f;
    }
    if (t < BB * MM) {
        P2[t] = make_float4(xyz2[3*t+0], xyz2[3*t+1], xyz2[3*t+2], 1.0f); // .w = remR
        stS[t] = 0.0f; stT[t] = 0.0f;
    }
    if (t < BB) out[t] = 0.0f;
}

// ---------------- col pass A: partial s,t ----------------
// lane = column; stream of i is wave-uniform -> scalar loads. No LDS, no barrier.
__global__ __launch_bounds__(256) void colA(
    const float4* __restrict__ P1, const float4* __restrict__ P2,
    float* __restrict__ stS, float* __restrict__ stT, float coef)
{
    const int chunks = NN / CH;                   // 16
    const int bpbatch = (MM / 256) * chunks;      // 128
    const int batch = blockIdx.x / bpbatch;
    const int rem   = blockIdx.x % bpbatch;
    const int cg    = rem / chunks;               // 256-col group 0..7
    const int ic    = rem % chunks;               // i-chunk
    const int col   = cg * 256 + threadIdx.x;

    const float4 q = P2[batch * MM + col];
    const float qx = q.x, qy = q.y, qz = q.z;
    const float4* __restrict__ p1 = P1 + batch * NN + ic * CH;

    float s = 0.0f, t = 0.0f;
#pragma unroll 4
    for (int ii = 0; ii < CH; ++ii) {
        const float4 a = p1[ii];                  // wave-uniform -> s_load
        const float dx = a.x - qx, dy = a.y - qy, dz = a.z - qz;
        const float d2 = dx*dx + dy*dy + dz*dz;
        const float se = a.w * __builtin_amdgcn_exp2f(coef * d2);
        s += se;
        t = fmaf(se, __builtin_amdgcn_sqrtf(d2), t);
    }
    atomicAdd(&stS[batch * MM + col], s);
    atomicAdd(&stT[batch * MM + col], t);
}

// ---------------- col pass B: finalize cons/remR/Pcol/cost, reset st ----------------
__global__ __launch_bounds__(256) void colB(
    float4* __restrict__ P2, float* __restrict__ Pcol,
    float* __restrict__ stS, float* __restrict__ stT,
    float* __restrict__ out)
{
    const int idx = blockIdx.x * 256 + threadIdx.x;   // 0 .. BB*MM-1
    const int batch = idx / MM;                       // block-uniform (2048 % 256 == 0)
    float* p2w = (float*)P2;
    const float R = p2w[4 * idx + 3];
    const float s = stS[idx], t = stT[idx];
    stS[idx] = 0.0f; stT[idx] = 0.0f;
    const float sumr = s * R;
    const float cons = fminf(R / (sumr + EPSF), 1.0f);
    Pcol[idx] = R * cons;
    p2w[4 * idx + 3] = fmaxf(R - sumr * cons, 0.0f);
    float c = R * cons * t;
#pragma unroll
    for (int off = 32; off > 0; off >>= 1) c += __shfl_xor(c, off, 64);
    if ((threadIdx.x & 63) == 0) atomicAdd(out + batch, c);
}

// ---------------- row pass ----------------
// MODE 0: first pass (remL == 1). MODE 1: fused remL update (e_prev=e_next^4) + new scale.
// MODE 2: last fused pass: e_prev direct, e_next = 1 (level 0).
template<int MODE>
__global__ __launch_bounds__(256) void row_pass(
    const float4* __restrict__ P2, const float* __restrict__ Pcol,
    float4* __restrict__ P1, float* __restrict__ remL,
    float coefPrev, float coefNext)
{
    __shared__ float4 sP2[MM];     // 32 KB
    __shared__ float  sPc[MM];     // 8 KB

    const int lane = threadIdx.x & 63;
    const int wave = threadIdx.x >> 6;
    const int bpb = NN / (WAVES * RB);          // 64
    const int batch = blockIdx.x / bpb;
    const int rblk  = blockIdx.x % bpb;
    const int r0 = rblk * (WAVES * RB) + wave * RB;

    {
        const float4* p2b = P2 + batch * MM;
        const float*  pcb = Pcol + batch * MM;
        for (int t = threadIdx.x; t < MM; t += 256) {
            sP2[t] = p2b[t];
            if (MODE != 0) sPc[t] = pcb[t];
        }
    }

    const float4* p1b = P1 + batch * NN;
    float px[RB], py[RB], pz[RB], psc[RB];
#pragma unroll
    for (int r = 0; r < RB; ++r) {
        const float4 q = p1b[r0 + r];
        px[r] = q.x; py[r] = q.y; pz[r] = q.z;
        psc[r] = (MODE != 0) ? q.w : 0.0f;
    }

    __syncthreads();

    const float cf = (MODE == 2) ? coefPrev : coefNext;

    float u[RB], rs[RB];
#pragma unroll
    for (int r = 0; r < RB; ++r) { u[r] = 0.0f; rs[r] = 0.0f; }

    for (int cb = 0; cb < MM; cb += 128) {
        const float4 qa = sP2[cb + lane];
        const float4 qb = sP2[cb + 64 + lane];
        const float Pca = (MODE != 0) ? sPc[cb + lane] : 0.0f;
        const float Pcb = (MODE != 0) ? sPc[cb + 64 + lane] : 0.0f;
        if (MODE == 2) rs[0] += qa.w + qb.w;

        float d2a[RB], d2b[RB];
#pragma unroll
        for (int r = 0; r < RB; ++r) {
            float dx = px[r] - qa.x, dy = py[r] - qa.y, dz = pz[r] - qa.z;
            d2a[r] = dx*dx + dy*dy + dz*dz;
            dx = px[r] - qb.x; dy = py[r] - qb.y; dz = pz[r] - qb.z;
            d2b[r] = dx*dx + dy*dy + dz*dz;
        }
        float ea[RB], eb[RB];
#pragma unroll
        for (int r = 0; r < RB; ++r) {
            ea[r] = __builtin_amdgcn_exp2f(cf * d2a[r]);
            eb[r] = __builtin_amdgcn_exp2f(cf * d2b[r]);
        }
#pragma unroll
        for (int r = 0; r < RB; ++r) {
            if (MODE == 0) {
                rs[r] = fmaf(ea[r], qa.w, rs[r]);
                rs[r] = fmaf(eb[r], qb.w, rs[r]);
            } else if (MODE == 1) {
                const float e2a = ea[r] * ea[r], e4a = e2a * e2a;
                const float e2b = eb[r] * eb[r], e4b = e2b * e2b;
                u[r]  = fmaf(e4a, Pca, u[r]);
                u[r]  = fmaf(e4b, Pcb, u[r]);
                rs[r] = fmaf(ea[r], qa.w, rs[r]);
                rs[r] = fmaf(eb[r], qb.w, rs[r]);
            } else {
                u[r]  = fmaf(ea[r], Pca, u[r]);
                u[r]  = fmaf(eb[r], Pcb, u[r]);
            }
        }
    }

#pragma unroll
    for (int r = 0; r < RB; ++r) {
#pragma unroll
        for (int off = 32; off > 0; off >>= 1) {
            if (MODE != 2 || r == 0) rs[r] += __shfl_xor(rs[r], off, 64);
            if (MODE != 0) u[r] += __shfl_xor(u[r], off, 64);
        }
    }

    float* p1w = (float*)P1;
#pragma unroll
    for (int r = 0; r < RB; ++r) {
        if (lane == r) {
            const int row = batch * NN + r0 + r;
            const float rsum = (MODE == 2) ? rs[0] : rs[r];
            float L;
            if (MODE == 0) {
                L = remL[row];
            } else {
                L = fmaxf(remL[row] - psc[r] * u[r], 0.0f);
                remL[row] = L;
            }
            p1w[4 * row + 3] = L / (rsum + EPSF);
        }
    }
}

extern "C" void kernel_launch(void* const* d_in, const int* in_sizes, int n_in,
                              void* d_out, int out_size, void* d_ws, size_t ws_size,
                              hipStream_t stream)
{
    const float* xyz1 = (const float*)d_in[0];
    const float* xyz2 = (const float*)d_in[1];
    float* out = (float*)d_out;

    const int BN = BB * NN, BM = BB * MM;
    float4* P1 = (float4*)d_ws;
    float4* P2 = P1 + BN;
    float*  remL = (float*)(P2 + BM);
    float*  Pcol = remL + BN;
    float*  stS  = Pcol + BM;
    float*  stT  = stS + BM;

    init_kernel<<<dim3((BN + 255) / 256), dim3(256), 0, stream>>>(
        xyz1, xyz2, P1, P2, remL, stS, stT, out);

    // levels: j = 7..-1 -> -(4^j), then 0.  coef = level * log2(e)
    float coef[10];
    const double lv[10] = {-16384.0, -4096.0, -1024.0, -256.0, -64.0,
                           -16.0, -4.0, -1.0, -0.25, 0.0};
    for (int i = 0; i < 10; ++i) coef[i] = (float)(lv[i] * 1.4426950408889634);

    dim3 rgrid(BB * (NN / (WAVES * RB)));            // 1024
    dim3 agrid(BB * (MM / 256) * (NN / CH));         // 2048
    dim3 bgrid((BB * MM) / 256);                     // 128
    dim3 blk(256);

    row_pass<0><<<rgrid, blk, 0, stream>>>(P2, Pcol, P1, remL, 0.0f, coef[0]);
    for (int j = 0; j < 10; ++j) {
        colA<<<agrid, blk, 0, stream>>>(P1, P2, stS, stT, coef[j]);
        colB<<<bgrid, blk, 0, stream>>>(P2, Pcol, stS, stT, out);
        if (j < 8) {
            row_pass<1><<<rgrid, blk, 0, stream>>>(P2, Pcol, P1, remL, coef[j], coef[j+1]);
        } else if (j == 8) {
            row_pass<2><<<rgrid, blk, 0, stream>>>(P2, Pcol, P1, remL, coef[8], 0.0f);
        }
    }
}